// Round 1
// baseline (265.138 us; speedup 1.0000x reference)
//
#include <hip/hip_runtime.h>
#include <math.h>

#define RANK 128
#define INV_T 20.0f      // 1 / 0.05
#define EPS_ARG 1e-7f

// ---------------- k_prep: normalize e1, compute nx and 1/(1-nx) ----------------
__global__ void k_prep(const float* __restrict__ emb, const int* __restrict__ lca,
                       const float* __restrict__ scale, float* __restrict__ e1ws) {
    __shared__ float wsum[2];
    __shared__ float bnorm;
    int i = threadIdx.x;               // 128 threads
    int lane = i & 63, w = i >> 6;
    float v = emb[(size_t)lca[0] * RANK + i];
    float sq = v * v;
#pragma unroll
    for (int o = 32; o; o >>= 1) sq += __shfl_down(sq, o);
    if (lane == 0) wsum[w] = sq;
    __syncthreads();
    if (i == 0) bnorm = sqrtf(wsum[0] + wsum[1]);
    __syncthreads();
    float s = fminf(fmaxf(scale[0], 0.01f), 1.0f - 0.001f);
    float e1n = v / fmaxf(bnorm, 1e-12f) * s;
    e1ws[i] = e1n;
    float sq2 = e1n * e1n;
#pragma unroll
    for (int o = 32; o; o >>= 1) sq2 += __shfl_down(sq2, o);
    __syncthreads();
    if (lane == 0) wsum[w] = sq2;
    __syncthreads();
    if (i == 0) {
        float nx = wsum[0] + wsum[1];
        e1ws[RANK]     = nx;
        e1ws[RANK + 1] = 1.0f / (1.0f - nx);
    }
}

// ---------------- k_leaf: per-leaf hyperbolic distance to e1 ----------------
__global__ void k_leaf(const float2* __restrict__ leaves, const float* __restrict__ e1ws,
                       float* __restrict__ D, int nLeaves) {
    __shared__ float2 se1[RANK / 2];
    __shared__ float snx[2];
    int t = threadIdx.x;               // 256 threads = 4 waves
    if (t < RANK / 2) se1[t] = ((const float2*)e1ws)[t];
    if (t == 0) { snx[0] = e1ws[RANK]; snx[1] = e1ws[RANK + 1]; }
    __syncthreads();
    int lane = t & 63, wid = t >> 6;
    int wavesPerBlock = blockDim.x >> 6;
    int gw = blockIdx.x * wavesPerBlock + wid;
    int nw = gridDim.x * wavesPerBlock;
    float nx = snx[0], invdx = snx[1];
    float2 e = se1[lane];
    for (int j = gw; j < nLeaves; j += nw) {
        float2 y = leaves[(size_t)j * (RANK / 2) + lane];   // 512B/wave coalesced
        float dot = y.x * e.x + y.y * e.y;
        float ny  = y.x * y.x + y.y * y.y;
#pragma unroll
        for (int o = 32; o; o >>= 1) {
            dot += __shfl_down(dot, o);
            ny  += __shfl_down(ny, o);
        }
        if (lane == 0) {
            float sq  = nx + ny - 2.0f * dot;                // ||x-y||^2
            float arg = 1.0f + 2.0f * sq * invdx / (1.0f - ny);
            arg = fmaxf(arg, 1.0f + EPS_ARG);
            D[j] = acoshf(arg);
        }
    }
}

// ---------------- k_pair1: t_p = (D[l]+D[r])/T, global max ----------------
__global__ void k_pair1(const int* __restrict__ li, const int* __restrict__ ri,
                        const float* __restrict__ D, float* __restrict__ t,
                        unsigned int* __restrict__ maxbits, int P) {
    float lm = 0.0f;
    int idx0 = blockIdx.x * blockDim.x + threadIdx.x;
    int stride = gridDim.x * blockDim.x;
    for (int p = idx0; p < P; p += stride) {
        float tp = (D[li[p]] + D[ri[p]]) * INV_T;
        t[p] = tp;
        lm = fmaxf(lm, tp);
    }
#pragma unroll
    for (int o = 32; o; o >>= 1) lm = fmaxf(lm, __shfl_down(lm, o));
    __shared__ float sm[8];
    int lane = threadIdx.x & 63, wid = threadIdx.x >> 6;
    if (lane == 0) sm[wid] = lm;
    __syncthreads();
    if (threadIdx.x == 0) {
        float m = sm[0];
        int nwv = blockDim.x >> 6;
        for (int i = 1; i < nwv; i++) m = fmaxf(m, sm[i]);
        atomicMax(maxbits, __float_as_uint(m));   // valid: all t >= 0
    }
}

// ---------------- k_pair2: Z, W, S sums ----------------
__global__ void k_pair2(const float* __restrict__ t, const float* __restrict__ sims,
                        const unsigned int* __restrict__ maxbits,
                        double* __restrict__ acc, int P) {
    float M = __uint_as_float(*maxbits);
    float z = 0.0f, w = 0.0f, s = 0.0f;
    int idx0 = blockIdx.x * blockDim.x + threadIdx.x;
    int stride = gridDim.x * blockDim.x;
    for (int p = idx0; p < P; p += stride) {
        float e = expf(t[p] - M);
        float sv = sims[p];
        z += e;
        w += sv * e;
        s += sv;
    }
#pragma unroll
    for (int o = 32; o; o >>= 1) {
        z += __shfl_down(z, o);
        w += __shfl_down(w, o);
        s += __shfl_down(s, o);
    }
    __shared__ double sz[8], sw[8], ss[8];
    int lane = threadIdx.x & 63, wid = threadIdx.x >> 6;
    if (lane == 0) { sz[wid] = z; sw[wid] = w; ss[wid] = s; }
    __syncthreads();
    if (threadIdx.x == 0) {
        double dz = 0, dw = 0, dsv = 0;
        int nwv = blockDim.x >> 6;
        for (int i = 0; i < nwv; i++) { dz += sz[i]; dw += sw[i]; dsv += ss[i]; }
        atomicAdd(&acc[0], dz);
        atomicAdd(&acc[1], dw);
        atomicAdd(&acc[2], dsv);
    }
}

// ---------------- k_fin ----------------
__global__ void k_fin(const double* __restrict__ acc, float* __restrict__ out) {
    out[0] = (float)(acc[2] - acc[1] / acc[0]);
}

extern "C" void kernel_launch(void* const* d_in, const int* in_sizes, int n_in,
                              void* d_out, int out_size, void* d_ws, size_t ws_size,
                              hipStream_t stream) {
    const int*   lca    = (const int*)d_in[0];
    const int*   li     = (const int*)d_in[1];
    const int*   ri     = (const int*)d_in[2];
    const float* sims   = (const float*)d_in[3];
    const float* emb    = (const float*)d_in[4];
    const float* leaves = (const float*)d_in[5];
    const float* scale  = (const float*)d_in[6];
    float* out = (float*)d_out;

    int P       = in_sizes[1];
    int nLeaves = in_sizes[5] / RANK;

    char* ws = (char*)d_ws;
    // layout: [0..4) maxbits, [8..32) acc doubles (Z,W,S), [64..) e1 (128+2 floats),
    //         [1024..) D[nLeaves], then t[P] (1KB-aligned)
    unsigned int* maxbits = (unsigned int*)ws;
    double*       acc     = (double*)(ws + 8);
    float*        e1ws    = (float*)(ws + 64);
    float*        D       = (float*)(ws + 1024);
    size_t Doff = 1024 + (((size_t)nLeaves * sizeof(float) + 1023) / 1024) * 1024;
    float*        t       = (float*)(ws + Doff);

    hipMemsetAsync(ws, 0, 64, stream);  // zero maxbits + acc
    k_prep <<<1, 128, 0, stream>>>(emb, lca, scale, e1ws);
    k_leaf <<<2048, 256, 0, stream>>>((const float2*)leaves, e1ws, D, nLeaves);
    k_pair1<<<1024, 256, 0, stream>>>(li, ri, D, t, maxbits, P);
    k_pair2<<<1024, 256, 0, stream>>>(t, sims, maxbits, acc, P);
    k_fin  <<<1, 1, 0, stream>>>(acc, out);
}

// Round 2
// 198.253 us; speedup vs baseline: 1.3374x; 1.3374x over previous
//
#include <hip/hip_runtime.h>
#include <math.h>

#define RANK 128
#define INV_T 20.0f      // 1 / 0.05
#define EPS_ARG 1e-7f
#define NBLK_PAIR 512

// ---------------- k_prep: normalize e1, compute nx and 1/(1-nx) ----------------
__global__ void k_prep(const float* __restrict__ emb, const int* __restrict__ lca,
                       const float* __restrict__ scale, float* __restrict__ e1ws) {
    __shared__ float wsum[2];
    __shared__ float bnorm;
    int i = threadIdx.x;               // 128 threads
    int lane = i & 63, w = i >> 6;
    float v = emb[(size_t)lca[0] * RANK + i];
    float sq = v * v;
#pragma unroll
    for (int o = 32; o; o >>= 1) sq += __shfl_down(sq, o);
    if (lane == 0) wsum[w] = sq;
    __syncthreads();
    if (i == 0) bnorm = sqrtf(wsum[0] + wsum[1]);
    __syncthreads();
    float s = fminf(fmaxf(scale[0], 0.01f), 1.0f - 0.001f);
    float e1n = v / fmaxf(bnorm, 1e-12f) * s;
    e1ws[i] = e1n;
    float sq2 = e1n * e1n;
#pragma unroll
    for (int o = 32; o; o >>= 1) sq2 += __shfl_down(sq2, o);
    __syncthreads();
    if (lane == 0) wsum[w] = sq2;
    __syncthreads();
    if (i == 0) {
        float nx = wsum[0] + wsum[1];
        e1ws[RANK]     = nx;
        e1ws[RANK + 1] = 1.0f / (1.0f - nx);
    }
}

// ---------------- k_leaf: per-leaf hyperbolic distance to e1 ----------------
// float4 loads; one wave handles 2 leaves (32-lane segments).
__global__ void k_leaf(const float4* __restrict__ leaves, const float* __restrict__ e1ws,
                       float* __restrict__ D, int nLeaves) {
    __shared__ float4 se1[RANK / 4];
    __shared__ float snx[2];
    int t = threadIdx.x;               // 256 threads = 4 waves
    if (t < RANK / 4) se1[t] = ((const float4*)e1ws)[t];
    if (t == 0) { snx[0] = e1ws[RANK]; snx[1] = e1ws[RANK + 1]; }
    __syncthreads();
    int lane = t & 63, wid = t >> 6;
    int l31  = lane & 31, half = lane >> 5;
    int wavesPerBlock = blockDim.x >> 6;
    int gw = blockIdx.x * wavesPerBlock + wid;   // global wave id
    int nw = gridDim.x * wavesPerBlock;
    float nx = snx[0], invdx = snx[1];
    float4 e = se1[l31];
    for (int jj = gw; 2 * jj < nLeaves; jj += nw) {
        int j = 2 * jj + half;
        float dot = 0.0f, ny = 0.0f;
        if (j < nLeaves) {
            float4 y = leaves[(size_t)j * (RANK / 4) + l31];   // 512B/row, 1KB/wave
            dot = y.x * e.x + y.y * e.y + y.z * e.z + y.w * e.w;
            ny  = y.x * y.x + y.y * y.y + y.z * y.z + y.w * y.w;
        }
#pragma unroll
        for (int o = 16; o; o >>= 1) {
            dot += __shfl_down(dot, o, 32);
            ny  += __shfl_down(ny, o, 32);
        }
        if (l31 == 0 && j < nLeaves) {
            float sq  = nx + ny - 2.0f * dot;                // ||x-y||^2
            float arg = 1.0f + 2.0f * sq * invdx / (1.0f - ny);
            arg = fmaxf(arg, 1.0f + EPS_ARG);
            D[j] = acoshf(arg);
        }
    }
}

// online-softmax combine: state (m, z, w); s is a plain sum
__device__ inline void comb(float& m, float& z, float& w, float& s,
                            float m2, float z2, float w2, float s2) {
    float mn = fmaxf(m, m2);
    float a = (m  == mn) ? 1.0f : __expf(m  - mn);
    float b = (m2 == mn) ? 1.0f : __expf(m2 - mn);
    z = z * a + z2 * b;
    w = w * a + w2 * b;
    m = mn;
    s += s2;
}

// ---------------- k_pair: fused distance-sum + online softmax partials ----------------
__global__ void k_pair(const int* __restrict__ li, const int* __restrict__ ri,
                       const float* __restrict__ sims, const float* __restrict__ D,
                       float4* __restrict__ partials, int P) {
    float m = -INFINITY, z = 0.0f, w = 0.0f, s = 0.0f;
    int tid = blockIdx.x * blockDim.x + threadIdx.x;
    int nthreads = gridDim.x * blockDim.x;
    int P4 = P >> 2;
    const int4*   li4 = (const int4*)li;
    const int4*   ri4 = (const int4*)ri;
    const float4* s4p = (const float4*)sims;
    for (int i = tid; i < P4; i += nthreads) {
        int4 l = li4[i], r = ri4[i];
        float4 sv = s4p[i];
        // issue all 8 gathers up front for MLP
        float a0 = D[l.x], b0 = D[r.x];
        float a1 = D[l.y], b1 = D[r.y];
        float a2 = D[l.z], b2 = D[r.z];
        float a3 = D[l.w], b3 = D[r.w];
        float t0 = (a0 + b0) * INV_T, t1 = (a1 + b1) * INV_T;
        float t2 = (a2 + b2) * INV_T, t3 = (a3 + b3) * INV_T;
#define STEP(tp, svv)                                                  \
        if (tp <= m) { float e = __expf(tp - m); z += e; w = fmaf(svv, e, w); } \
        else { float rr = __expf(m - tp); z = fmaf(z, rr, 1.0f); w = fmaf(w, rr, svv); m = tp; } \
        s += svv;
        STEP(t0, sv.x) STEP(t1, sv.y) STEP(t2, sv.z) STEP(t3, sv.w)
    }
    // scalar tail (P % 4)
    int tail0 = P4 << 2;
    for (int p = tail0 + tid; p < P; p += nthreads) {
        float tp = (D[li[p]] + D[ri[p]]) * INV_T;
        float svv = sims[p];
        STEP(tp, svv)
    }
#undef STEP
    // wave butterfly combine
#pragma unroll
    for (int o = 32; o; o >>= 1) {
        float m2 = __shfl_xor(m, o), z2 = __shfl_xor(z, o);
        float w2 = __shfl_xor(w, o), s2 = __shfl_xor(s, o);
        comb(m, z, w, s, m2, z2, w2, s2);
    }
    __shared__ float4 sp[8];
    int lane = threadIdx.x & 63, wid = threadIdx.x >> 6;
    if (lane == 0) sp[wid] = make_float4(m, z, w, s);
    __syncthreads();
    if (threadIdx.x == 0) {
        int nwv = blockDim.x >> 6;
        for (int i = 1; i < nwv; i++) {
            float4 q = sp[i];
            comb(m, z, w, s, q.x, q.y, q.z, q.w);
        }
        partials[blockIdx.x] = make_float4(m, z, w, s);
    }
}

// ---------------- k_fin: reduce per-block partials ----------------
__global__ void k_fin(const float4* __restrict__ partials, float* __restrict__ out, int nb) {
    int t = threadIdx.x;               // 256 threads
    float m = -INFINITY, z = 0.0f, w = 0.0f, s = 0.0f;
    for (int i = t; i < nb; i += blockDim.x) {
        float4 q = partials[i];
        comb(m, z, w, s, q.x, q.y, q.z, q.w);
    }
#pragma unroll
    for (int o = 32; o; o >>= 1) {
        float m2 = __shfl_xor(m, o), z2 = __shfl_xor(z, o);
        float w2 = __shfl_xor(w, o), s2 = __shfl_xor(s, o);
        comb(m, z, w, s, m2, z2, w2, s2);
    }
    __shared__ float4 sp[4];
    int lane = t & 63, wid = t >> 6;
    if (lane == 0) sp[wid] = make_float4(m, z, w, s);
    __syncthreads();
    if (t == 0) {
        for (int i = 1; i < (int)(blockDim.x >> 6); i++) {
            float4 q = sp[i];
            comb(m, z, w, s, q.x, q.y, q.z, q.w);
        }
        out[0] = s - w / z;
    }
}

extern "C" void kernel_launch(void* const* d_in, const int* in_sizes, int n_in,
                              void* d_out, int out_size, void* d_ws, size_t ws_size,
                              hipStream_t stream) {
    const int*   lca    = (const int*)d_in[0];
    const int*   li     = (const int*)d_in[1];
    const int*   ri     = (const int*)d_in[2];
    const float* sims   = (const float*)d_in[3];
    const float* emb    = (const float*)d_in[4];
    const float* leaves = (const float*)d_in[5];
    const float* scale  = (const float*)d_in[6];
    float* out = (float*)d_out;

    int P       = in_sizes[1];
    int nLeaves = in_sizes[5] / RANK;

    char* ws = (char*)d_ws;
    // layout: [0..1024) e1 (128+2 floats); [1024..) D[nLeaves]; then partials (16B-aligned)
    float* e1ws = (float*)ws;
    float* D    = (float*)(ws + 1024);
    size_t poff = 1024 + (((size_t)nLeaves * sizeof(float) + 1023) / 1024) * 1024;
    float4* partials = (float4*)(ws + poff);

    k_prep<<<1, 128, 0, stream>>>(emb, lca, scale, e1ws);
    k_leaf<<<2048, 256, 0, stream>>>((const float4*)leaves, e1ws, D, nLeaves);
    k_pair<<<NBLK_PAIR, 256, 0, stream>>>(li, ri, sims, D, partials, P);
    k_fin <<<1, 256, 0, stream>>>(partials, out, NBLK_PAIR);
}